// Round 1
// 1425.432 us; speedup vs baseline: 5.8244x; 5.8244x over previous
//
#include <hip/hip_runtime.h>

constexpr int   kN     = 64;    // tokens per window (8x8)
constexpr int   kC     = 180;   // channels
constexpr int   kH     = 6;     // heads
constexpr int   kHD    = 30;    // head dim
constexpr float kScale = 0.18257418583505536f; // 30^-0.5

typedef short bf16x8 __attribute__((ext_vector_type(8)));
typedef float f32x4  __attribute__((ext_vector_type(4)));
typedef unsigned short u16;

// ---------------- workspace layout (bytes) ----------------
// qw2: [h6][ct6][ks6][s2][lane64][8] bf16   (s=0 hi plane, s=1 lo plane)
constexpr size_t kQW2Off = 0;
constexpr size_t kQW2Sz  = (size_t)6*6*6*2*64*8*2;   // 442368
// pw2: [ct12][ks6][s2][lane64][8] bf16
constexpr size_t kPW2Off = kQW2Off + kQW2Sz;
constexpr size_t kPW2Sz  = (size_t)12*6*2*64*8*2;    // 147456
// qb2: [h6][ct6][16] f32  (scale folded into q)
constexpr size_t kQB2Off = kPW2Off + kPW2Sz;
constexpr size_t kQB2Sz  = (size_t)6*6*16*4;         // 2304
// pb2: [ct12][16] f32
constexpr size_t kPB2Off = kQB2Off + kQB2Sz;
constexpr size_t kPB2Sz  = (size_t)12*16*4;          // 768
// biasx: [h6][64][64] f32  (expanded rel-pos bias)
constexpr size_t kBXOff  = kPB2Off + kPB2Sz;
constexpr size_t kBXSz   = (size_t)6*64*64*4;        // 98304
constexpr size_t kWsNeed = kBXOff + kBXSz;           // 691200

__device__ __forceinline__ float u2f(u16 u) {
    return __uint_as_float(((unsigned int)u) << 16);
}
__device__ __forceinline__ u16 f2u(float v) {
    unsigned int x = __float_as_uint(v);
    return (u16)((x + 0x7FFFu + ((x >> 16) & 1u)) >> 16);
}
__device__ __forceinline__ unsigned pack2(float a, float b) {
    return (unsigned)f2u(a) | ((unsigned)f2u(b) << 16);
}
__device__ __forceinline__ int swz4(int row) { return (row ^ (row >> 2)) & 3; }

// ---------------------------------------------------------------------------
// Prep: split weights into bf16 hi/lo in MFMA B-fragment order, fold q-scale,
// pad to 32/192, expand rel-pos bias table. 43776 items total.
// ---------------------------------------------------------------------------
__global__ __launch_bounds__(256) void wmsa_prep(
    const float* __restrict__ qkv_w, const float* __restrict__ qkv_b,
    const float* __restrict__ proj_w, const float* __restrict__ proj_b,
    const float* __restrict__ rpb, char* __restrict__ wsb)
{
    const int id = blockIdx.x * 256 + threadIdx.x;
    u16*   qw2 = (u16*)(wsb + kQW2Off);
    u16*   pw2 = (u16*)(wsb + kPW2Off);
    float* qb2 = (float*)(wsb + kQB2Off);
    float* pb2 = (float*)(wsb + kPB2Off);
    float* bx  = (float*)(wsb + kBXOff);

    if (id < 13824) {                          // qkv weight fragments
        const int l = id & 63;
        int t = id >> 6;
        const int ksb = t % 6; t /= 6;
        const int ct  = t % 6; t /= 6;
        const int h   = t;
        const int which = ct >> 1;             // 0=q 1=k 2=v
        const int dsub  = ((ct & 1) << 4) + (l & 15);
        const int g     = which * kC + h * kHD + dsub;
        const float s   = (which == 0) ? kScale : 1.f;
        const size_t base = ((size_t)((h*6 + ct)*6 + ksb) * 2) * 512 + (size_t)l * 8;
        #pragma unroll
        for (int j = 0; j < 8; ++j) {
            const int k = ksb*32 + ((l >> 4) << 3) + j;
            float v = (dsub < kHD && k < kC) ? qkv_w[(size_t)g*kC + k] * s : 0.f;
            u16 hb = f2u(v);
            qw2[base + j]       = hb;
            qw2[base + 512 + j] = f2u(v - u2f(hb));
        }
    } else if (id < 13824 + 4608) {            // proj weight fragments
        const int id2 = id - 13824;
        const int l = id2 & 63;
        int t = id2 >> 6;
        const int ksb = t % 6;
        const int ct  = t / 6;                 // 0..11
        const int col = ct*16 + (l & 15);
        const size_t base = ((size_t)(ct*6 + ksb) * 2) * 512 + (size_t)l * 8;
        #pragma unroll
        for (int j = 0; j < 8; ++j) {
            const int k = ksb*32 + ((l >> 4) << 3) + j;
            float v = (col < kC && k < kC) ? proj_w[(size_t)col*kC + k] : 0.f;
            u16 hb = f2u(v);
            pw2[base + j]       = hb;
            pw2[base + 512 + j] = f2u(v - u2f(hb));
        }
    } else if (id < 13824 + 4608 + 576) {      // qkv bias (pad->0, q scaled)
        const int id2 = id - (13824 + 4608);
        const int cc = id2 & 15;
        int t = id2 >> 4;
        const int ct = t % 6;
        const int h  = t / 6;
        const int which = ct >> 1;
        const int dsub  = ((ct & 1) << 4) + cc;
        float v = (dsub < kHD) ? qkv_b[which*kC + h*kHD + dsub] : 0.f;
        if (which == 0) v *= kScale;
        qb2[(h*6 + ct)*16 + cc] = v;
    } else if (id < 13824 + 4608 + 576 + 192) { // proj bias
        const int id2 = id - (13824 + 4608 + 576);
        const int cc = id2 & 15;
        const int ct = id2 >> 4;
        const int col = ct*16 + cc;
        pb2[id2] = (col < kC) ? proj_b[col] : 0.f;
    } else if (id < 43776) {                   // expand rel-pos bias
        const int id2 = id - 19200;
        const int j = id2 & 63;
        int t = id2 >> 6;
        const int i = t & 63;
        const int h = t >> 6;
        const int yi = i >> 3, xi = i & 7, yj = j >> 3, xj = j & 7;
        const int ridx = (yi - yj + 7) * 15 + (xi - xj + 7);
        bx[(h*64 + i)*64 + j] = rpb[ridx*kH + h];
    }
}

// ---------------------------------------------------------------------------
// Fused W-MSA: one block per window, 6 waves (one head per wave).
// MFMA 16x16x32 bf16 throughout; split-bf16 (hi+lo) weights for fp32-grade
// weight accuracy; proj fused (attn round-trips through LDS, not HBM).
// LDS: xs 24576 + 6 * (qs 4096 + kls 4096 + vt 4096 + ps 2048) = 110592 B.
// ---------------------------------------------------------------------------
__global__ __launch_bounds__(384, 1) void wmsa_fused(
    const float* __restrict__ x, const float* __restrict__ mask,
    const char* __restrict__ wsb, float* __restrict__ out, int nw_per_img)
{
    extern __shared__ char smem[];
    const int w    = blockIdx.x;
    const int tid  = threadIdx.x;
    const int wave = tid >> 6;
    const int lane = tid & 63;
    const int c    = lane & 15;
    const int p    = lane >> 4;

    u16* xs = (u16*)smem;                     // [64][192] bf16, slot^=(row&7)
    char* wb = smem + 24576 + wave * 14336;
    u16* qs  = (u16*)wb;                      // [64][32] bf16, slot^=swz4(row)
    u16* kls = (u16*)(wb + 4096);             // [64][32] bf16
    u16* vt  = (u16*)(wb + 8192);             // [32][64] bf16 (V^T), slot^=(d&7)
    u16* ps  = (u16*)(wb + 12288);            // [16][64] bf16 (P tile), slot^=(c&7)

    const u16*   qw2 = (const u16*)(wsb + kQW2Off);
    const u16*   pw2 = (const u16*)(wsb + kPW2Off);
    const float* qb2 = (const float*)(wsb + kQB2Off);
    const float* pb2 = (const float*)(wsb + kPB2Off);
    const float* bxg = (const float*)(wsb + kBXOff);

    // ---- stage x[w] -> LDS bf16, padded K 180->192, swizzled ----
    const float* xg = x + (size_t)w * (kN * kC);
    for (int it = tid; it < 64 * 24; it += 384) {
        const int row  = it / 24;
        const int slot = it - row * 24;
        const int k0   = slot * 8;
        float4 f0 = {0.f,0.f,0.f,0.f}, f1 = {0.f,0.f,0.f,0.f};
        if (k0 + 8 <= kC) {
            f0 = *(const float4*)(xg + row*kC + k0);
            f1 = *(const float4*)(xg + row*kC + k0 + 4);
        } else if (k0 < kC) {                  // slot 22: k 176..179 valid
            f0 = *(const float4*)(xg + row*kC + k0);
        }
        uint4 u;
        u.x = pack2(f0.x, f0.y); u.y = pack2(f0.z, f0.w);
        u.z = pack2(f1.x, f1.y); u.w = pack2(f1.z, f1.w);
        *(uint4*)(xs + row*192 + (slot ^ (row & 7))*8) = u;
    }
    __syncthreads();

    // =================== QKV (this wave's head) ===================
    {
        const int h = wave;
        #pragma unroll
        for (int cg = 0; cg < 2; ++cg) {       // 2 groups of 3 col-tiles
            f32x4 acc[3][4];
            #pragma unroll
            for (int a1 = 0; a1 < 3; ++a1)
                #pragma unroll
                for (int a2 = 0; a2 < 4; ++a2) acc[a1][a2] = f32x4{0.f,0.f,0.f,0.f};

            #pragma unroll
            for (int ksb = 0; ksb < 6; ++ksb) {
                bf16x8 a[4];
                #pragma unroll
                for (int mi = 0; mi < 4; ++mi) {
                    const int row = mi*16 + c;
                    const int sl  = (ksb*4 + p) ^ (row & 7);
                    a[mi] = *(const bf16x8*)(xs + row*192 + sl*8);
                }
                #pragma unroll
                for (int ctl = 0; ctl < 3; ++ctl) {
                    const int ct = cg*3 + ctl;
                    const u16* wp = qw2 + ((size_t)((h*6 + ct)*6 + ksb) * 2) * 512 + (size_t)lane * 8;
                    const bf16x8 bhi = *(const bf16x8*)(wp);
                    const bf16x8 blo = *(const bf16x8*)(wp + 512);
                    #pragma unroll
                    for (int mi = 0; mi < 4; ++mi) {
                        acc[ctl][mi] = __builtin_amdgcn_mfma_f32_16x16x32_bf16(a[mi], bhi, acc[ctl][mi], 0, 0, 0);
                        acc[ctl][mi] = __builtin_amdgcn_mfma_f32_16x16x32_bf16(a[mi], blo, acc[ctl][mi], 0, 0, 0);
                    }
                }
            }
            // epilogue: +bias, store q/k row-major, v transposed
            #pragma unroll
            for (int ctl = 0; ctl < 3; ++ctl) {
                const int ct = cg*3 + ctl;
                const int which = ct >> 1;
                const float bb = qb2[(wave*6 + ct)*16 + c];
                if (which < 2) {
                    u16* dst = (which == 0) ? qs : kls;
                    const int col = ((ct & 1) << 4) + c;   // 0..31 within q|k
                    #pragma unroll
                    for (int mi = 0; mi < 4; ++mi)
                        #pragma unroll
                        for (int r = 0; r < 4; ++r) {
                            const int row = mi*16 + p*4 + r;
                            const int sl  = (col >> 3) ^ swz4(row);
                            dst[row*32 + sl*8 + (col & 7)] = f2u(acc[ctl][mi][r] + bb);
                        }
                } else {
                    const int d = ((ct & 1) << 4) + c;     // 0..31
                    #pragma unroll
                    for (int mi = 0; mi < 4; ++mi) {
                        ushort4 hv;
                        hv.x = f2u(acc[ctl][mi][0] + bb);
                        hv.y = f2u(acc[ctl][mi][1] + bb);
                        hv.z = f2u(acc[ctl][mi][2] + bb);
                        hv.w = f2u(acc[ctl][mi][3] + bb);
                        const int tok0 = mi*16 + p*4;
                        const int sl   = (tok0 >> 3) ^ (d & 7);
                        *(ushort4*)(vt + d*64 + sl*8 + (tok0 & 7)) = hv;
                    }
                }
            }
        }
    }
    __syncthreads();   // all waves done reading xs; attention may overwrite it

    // =================== attention (S^T = K @ Q^T) ===================
    {
        const int h = wave;
        bf16x8 ak[4], bq[4];
        #pragma unroll
        for (int t = 0; t < 4; ++t) {
            const int row = t*16 + c;
            const int sl  = p ^ swz4(row);
            ak[t] = *(const bf16x8*)(kls + row*32 + sl*8);
            bq[t] = *(const bf16x8*)(qs  + row*32 + sl*8);
        }
        f32x4 st[4][4];    // [mj][ni]: lane holds S[j=16mj+4p+r][i=16ni+c]
        const f32x4 fz = {0.f,0.f,0.f,0.f};
        #pragma unroll
        for (int mj = 0; mj < 4; ++mj)
            #pragma unroll
            for (int ni = 0; ni < 4; ++ni)
                st[mj][ni] = __builtin_amdgcn_mfma_f32_16x16x32_bf16(ak[mj], bq[ni], fz, 0, 0, 0);

        // + rel-pos bias + mask
        const float* bx = bxg + h * 4096;
        const float* mk = mask + (size_t)(w % nw_per_img) * 4096;
        #pragma unroll
        for (int ni = 0; ni < 4; ++ni) {
            const int i = ni*16 + c;
            #pragma unroll
            for (int mj = 0; mj < 4; ++mj) {
                const int j0 = mj*16 + p*4;
                const float4 bb = *(const float4*)(bx + i*64 + j0);
                const float4 mm = *(const float4*)(mk + i*64 + j0);
                st[mj][ni][0] += bb.x + mm.x;
                st[mj][ni][1] += bb.y + mm.y;
                st[mj][ni][2] += bb.z + mm.z;
                st[mj][ni][3] += bb.w + mm.w;
            }
        }
        // softmax over j (16 in-lane + shfl over lane bits 4,5)
        float inv[4];
        #pragma unroll
        for (int ni = 0; ni < 4; ++ni) {
            float mx = -3.4e38f;
            #pragma unroll
            for (int mj = 0; mj < 4; ++mj)
                #pragma unroll
                for (int r = 0; r < 4; ++r) mx = fmaxf(mx, st[mj][ni][r]);
            mx = fmaxf(mx, __shfl_xor(mx, 16));
            mx = fmaxf(mx, __shfl_xor(mx, 32));
            float s = 0.f;
            #pragma unroll
            for (int mj = 0; mj < 4; ++mj)
                #pragma unroll
                for (int r = 0; r < 4; ++r) {
                    const float e = __expf(st[mj][ni][r] - mx);
                    st[mj][ni][r] = e; s += e;
                }
            s += __shfl_xor(s, 16);
            s += __shfl_xor(s, 32);
            inv[ni] = 1.f / s;
        }
        // PV per output row-tile (stage 16x64 P tile via LDS, then 2 ksteps)
        f32x4 oacc[4][2];
        #pragma unroll
        for (int a1 = 0; a1 < 4; ++a1)
            #pragma unroll
            for (int a2 = 0; a2 < 2; ++a2) oacc[a1][a2] = fz;

        #pragma unroll
        for (int ni = 0; ni < 4; ++ni) {
            #pragma unroll
            for (int mj = 0; mj < 4; ++mj) {
                ushort4 pk;
                pk.x = f2u(st[mj][ni][0] * inv[ni]);
                pk.y = f2u(st[mj][ni][1] * inv[ni]);
                pk.z = f2u(st[mj][ni][2] * inv[ni]);
                pk.w = f2u(st[mj][ni][3] * inv[ni]);
                const int j0 = mj*16 + p*4;
                const int sl = (j0 >> 3) ^ (c & 7);
                *(ushort4*)(ps + c*64 + sl*8 + (j0 & 7)) = pk;
            }
            #pragma unroll
            for (int k2 = 0; k2 < 2; ++k2) {
                const int sl = (k2*4 + p) ^ (c & 7);
                const bf16x8 ap = *(const bf16x8*)(ps + c*64 + sl*8);
                #pragma unroll
                for (int dt = 0; dt < 2; ++dt) {
                    const int d = dt*16 + c;            // d&7 == c&7 -> same sl
                    const bf16x8 bv = *(const bf16x8*)(vt + d*64 + sl*8);
                    oacc[ni][dt] = __builtin_amdgcn_mfma_f32_16x16x32_bf16(ap, bv, oacc[ni][dt], 0, 0, 0);
                }
            }
        }
        // write this head's attn slice into xs (bf16), channels h*30+d
        #pragma unroll
        for (int mi = 0; mi < 4; ++mi)
            #pragma unroll
            for (int dt = 0; dt < 2; ++dt) {
                const int d = dt*16 + c;
                if (d < kHD) {
                    const int kx = wave*kHD + d;
                    #pragma unroll
                    for (int r = 0; r < 4; ++r) {
                        const int row = mi*16 + p*4 + r;
                        const int sl  = (kx >> 3) ^ (row & 7);
                        xs[row*192 + sl*8 + (kx & 7)] = f2u(oacc[mi][dt][r]);
                    }
                }
            }
    }
    __syncthreads();   // xs now holds full 64x180 attn output (pad still 0)

    // =================== output projection ===================
    {
        f32x4 pacc[2][4];
        #pragma unroll
        for (int a1 = 0; a1 < 2; ++a1)
            #pragma unroll
            for (int a2 = 0; a2 < 4; ++a2) pacc[a1][a2] = f32x4{0.f,0.f,0.f,0.f};

        #pragma unroll
        for (int ksb = 0; ksb < 6; ++ksb) {
            bf16x8 a[4];
            #pragma unroll
            for (int mi = 0; mi < 4; ++mi) {
                const int row = mi*16 + c;
                const int sl  = (ksb*4 + p) ^ (row & 7);
                a[mi] = *(const bf16x8*)(xs + row*192 + sl*8);
            }
            #pragma unroll
            for (int ctl = 0; ctl < 2; ++ctl) {
                const int ct = wave*2 + ctl;
                const u16* wp = pw2 + ((size_t)(ct*6 + ksb) * 2) * 512 + (size_t)lane * 8;
                const bf16x8 bhi = *(const bf16x8*)(wp);
                const bf16x8 blo = *(const bf16x8*)(wp + 512);
                #pragma unroll
                for (int mi = 0; mi < 4; ++mi) {
                    pacc[ctl][mi] = __builtin_amdgcn_mfma_f32_16x16x32_bf16(a[mi], bhi, pacc[ctl][mi], 0, 0, 0);
                    pacc[ctl][mi] = __builtin_amdgcn_mfma_f32_16x16x32_bf16(a[mi], blo, pacc[ctl][mi], 0, 0, 0);
                }
            }
        }
        float* og = out + (size_t)w * (kN * kC);
        #pragma unroll
        for (int ctl = 0; ctl < 2; ++ctl) {
            const int ct  = wave*2 + ctl;
            const int col = ct*16 + c;
            if (col < kC) {
                const float bb = pb2[ct*16 + c];
                #pragma unroll
                for (int mi = 0; mi < 4; ++mi)
                    #pragma unroll
                    for (int r = 0; r < 4; ++r)
                        og[(mi*16 + p*4 + r)*kC + col] = pacc[ctl][mi][r] + bb;
            }
        }
    }
}

extern "C" void kernel_launch(void* const* d_in, const int* in_sizes, int n_in,
                              void* d_out, int out_size, void* d_ws, size_t ws_size,
                              hipStream_t stream) {
    const float* x      = (const float*)d_in[0];
    const float* mask   = (const float*)d_in[1];
    const float* qkv_w  = (const float*)d_in[2];
    const float* qkv_b  = (const float*)d_in[3];
    const float* proj_w = (const float*)d_in[4];
    const float* proj_b = (const float*)d_in[5];
    const float* rpb    = (const float*)d_in[6];
    float* out = (float*)d_out;

    const int nW         = in_sizes[0] / (kN * kC);     // 8192
    const int nw_per_img = in_sizes[1] / (kN * kN);     // 1024

    if (ws_size < kWsNeed) return;   // workspace too small: refuse to corrupt

    constexpr int kLds = 24576 + 6 * 14336;  // 110592 B
    static bool attr_set = false;
    if (!attr_set) {
        hipFuncSetAttribute((const void*)wmsa_fused,
                            hipFuncAttributeMaxDynamicSharedMemorySize, kLds);
        attr_set = true;
    }

    wmsa_prep<<<171, 256, 0, stream>>>(qkv_w, qkv_b, proj_w, proj_b, rpb, (char*)d_ws);
    wmsa_fused<<<nW, 384, kLds, stream>>>(x, mask, (const char*)d_ws, out, nw_per_img);
}